// Round 1
// baseline (281.671 us; speedup 1.0000x reference)
//
#include <hip/hip_runtime.h>
#include <hip/hip_bf16.h>

// Problem dims (fixed by reference)
constexpr int BB  = 64;    // batch
constexpr int SS  = 512;   // seq len
constexpr int HH  = 768;   // hidden
constexpr int NL  = 9;     // labels
constexpr int NROWS = BB * SS;          // 32768
constexpr int EMN   = SS * NL;          // 4608 emissions per batch

// ---------------------------------------------------------------------------
// Kernel 1: logits[b,s,l] = hidden[b,s,:] @ W[:,l] + bias[l]
// One wave per row. Lane loads 3 float4 of hidden (coalesced); the matching
// 12 rows x 9 cols of W live in registers (preloaded once per thread).
// ---------------------------------------------------------------------------
__global__ __launch_bounds__(256, 2) void logits_kernel(
    const float* __restrict__ hidden, const float* __restrict__ W,
    const float* __restrict__ bias, float* __restrict__ logits) {
  const int lane   = threadIdx.x & 63;
  const int wid    = blockIdx.x * (blockDim.x >> 6) + (threadIdx.x >> 6);
  const int nwaves = gridDim.x * (blockDim.x >> 6);

  // Preload W fragments: element index e = 4*lane + 256*j + k  (j=0..2,k=0..3)
  float w[3][4][NL];
#pragma unroll
  for (int j = 0; j < 3; ++j)
#pragma unroll
    for (int k = 0; k < 4; ++k) {
      const int r = lane * 4 + j * 256 + k;
#pragma unroll
      for (int l = 0; l < NL; ++l) w[j][k][l] = W[r * NL + l];
    }
  const float my_bias = (lane < NL) ? bias[lane] : 0.0f;

  for (int row = wid; row < NROWS; row += nwaves) {
    const float4* hp = (const float4*)(hidden + (size_t)row * HH);
    float acc[NL];
#pragma unroll
    for (int l = 0; l < NL; ++l) acc[l] = 0.0f;
#pragma unroll
    for (int j = 0; j < 3; ++j) {
      const float4 h = hp[lane + j * 64];
#pragma unroll
      for (int l = 0; l < NL; ++l)
        acc[l] += h.x * w[j][0][l] + h.y * w[j][1][l] +
                  h.z * w[j][2][l] + h.w * w[j][3][l];
    }
    // 64-lane butterfly reduce for all 9 sums
#pragma unroll
    for (int off = 32; off >= 1; off >>= 1)
#pragma unroll
      for (int l = 0; l < NL; ++l) acc[l] += __shfl_xor(acc[l], off, 64);
    if (lane < NL) {
      float v = acc[0];
#pragma unroll
      for (int l = 1; l < NL; ++l) if (lane == l) v = acc[l];
      logits[(size_t)row * NL + lane] = v + my_bias;
    }
  }
}

// ---------------------------------------------------------------------------
// Kernel 2: per-batch CRF. 192 blocks x 64 threads (1 wave).
//   role 0 (blocks   0.. 63): log-normalizer (forward algorithm)
//   role 1 (blocks  64..127): viterbi + backtrace + one-hot output
//   role 2 (blocks 128..191): numerator (gold-path score)
// Replicated-score scheme: every lane keeps all 9 scores in registers; lane j
// computes next score j; 9 shuffles re-replicate. Mask is a prefix: steps
// t >= len are identity, so we just stop at len.
// ---------------------------------------------------------------------------
__global__ __launch_bounds__(64) void crf_kernel(
    const float* __restrict__ logits, const int* __restrict__ mask,
    const int* __restrict__ labels, const float* __restrict__ start_t,
    const float* __restrict__ end_t, const float* __restrict__ trans,
    float* __restrict__ out, float* __restrict__ num_den) {
  __shared__ float em[EMN];                 // 18 KB: this batch's emissions
  __shared__ float tr_s[NL * NL];
  __shared__ int   lab[SS];
  __shared__ unsigned char bp[EMN];         // viterbi backpointers
  __shared__ unsigned char tags[SS];
  __shared__ int   len_s;

  const int role = blockIdx.x >> 6;
  const int b    = blockIdx.x & 63;
  const int tid  = threadIdx.x;

  // Stage emissions + transitions + length (coalesced)
  for (int i = tid; i < EMN; i += 64) em[i] = logits[(size_t)b * EMN + i];
  for (int i = tid; i < NL * NL; i += 64) tr_s[i] = trans[i];
  int lsum = 0;
  for (int t = tid; t < SS; t += 64) lsum += mask[b * SS + t];
#pragma unroll
  for (int off = 32; off >= 1; off >>= 1) lsum += __shfl_xor(lsum, off, 64);
  if (tid == 0) len_s = lsum;
  if (role == 2) {
    for (int t = tid; t < SS; t += 64) {
      const int v = labels[b * SS + t];
      lab[t] = (v == -100) ? 0 : v;
    }
  }
  __syncthreads();
  const int len = len_s;   // in [256, 512]; mask[t] = (t < len)

  if (role == 0) {
    // ---- log-normalizer ----
    const int j = (tid < NL) ? tid : 0;
    float tcol[NL];
#pragma unroll
    for (int i = 0; i < NL; ++i) tcol[i] = tr_s[i * NL + j];
    float s[NL];
#pragma unroll
    for (int i = 0; i < NL; ++i) s[i] = start_t[i] + em[i];
    for (int t = 1; t < len; ++t) {
      float c[NL];
#pragma unroll
      for (int i = 0; i < NL; ++i) c[i] = s[i] + tcol[i];
      float m = c[0];
#pragma unroll
      for (int i = 1; i < NL; ++i) m = fmaxf(m, c[i]);
      float sum = 0.0f;
#pragma unroll
      for (int i = 0; i < NL; ++i) sum += __expf(c[i] - m);
      const float nxt = m + __logf(sum) + em[t * NL + j];
#pragma unroll
      for (int i = 0; i < NL; ++i) s[i] = __shfl(nxt, i, 64);
    }
    // den = logsumexp(s + end_t)
    float c[NL];
#pragma unroll
    for (int i = 0; i < NL; ++i) c[i] = s[i] + end_t[i];
    float m = c[0];
#pragma unroll
    for (int i = 1; i < NL; ++i) m = fmaxf(m, c[i]);
    float sum = 0.0f;
#pragma unroll
    for (int i = 0; i < NL; ++i) sum += __expf(c[i] - m);
    if (tid == 0) num_den[64 + b] = m + __logf(sum);

  } else if (role == 1) {
    // ---- viterbi ----
    const int j = (tid < NL) ? tid : 0;
    float tcol[NL];
#pragma unroll
    for (int i = 0; i < NL; ++i) tcol[i] = tr_s[i * NL + j];
    float s[NL];
#pragma unroll
    for (int i = 0; i < NL; ++i) s[i] = start_t[i] + em[i];
    for (int t = 1; t < len; ++t) {
      float best = s[0] + tcol[0];
      int   arg  = 0;
#pragma unroll
      for (int i = 1; i < NL; ++i) {
        const float c = s[i] + tcol[i];
        if (c > best) { best = c; arg = i; }   // strict >: first-max like jnp
      }
      if (tid < NL) bp[t * NL + j] = (unsigned char)arg;
      const float nxt = best + em[t * NL + j];
#pragma unroll
      for (int i = 0; i < NL; ++i) s[i] = __shfl(nxt, i, 64);
    }
    int   bl = 0;
    float bv = s[0] + end_t[0];
#pragma unroll
    for (int i = 1; i < NL; ++i) {
      const float c = s[i] + end_t[i];
      if (c > bv) { bv = c; bl = i; }
    }
    __syncthreads();                 // bp visible to lane 0
    if (tid == 0) {
      int cur = bl;
      for (int t = SS - 1; t >= len - 1; --t) tags[t] = (unsigned char)cur;
      for (int t = len - 1; t >= 1; --t) {
        cur = bp[t * NL + cur];
        tags[t - 1] = (unsigned char)cur;
      }
    }
    __syncthreads();
    // one-hot * mask output (also writes the required zeros)
    for (int idx = tid; idx < EMN; idx += 64) {
      const int t = idx / NL;
      const int l = idx - t * NL;
      out[1 + (size_t)b * EMN + idx] =
          (t < len && l == (int)tags[t]) ? 1.0f : 0.0f;
    }

  } else {
    // ---- numerator (gold path score), parallel over t ----
    float contrib = 0.0f;
    for (int t = tid; t < SS; t += 64) {
      if (t >= 1 && t < len)
        contrib += em[t * NL + lab[t]] + tr_s[lab[t - 1] * NL + lab[t]];
    }
#pragma unroll
    for (int off = 32; off >= 1; off >>= 1)
      contrib += __shfl_xor(contrib, off, 64);
    if (tid == 0) {
      const int l0 = lab[0];
      num_den[b] = start_t[l0] + em[l0] + contrib + end_t[lab[len - 1]];
    }
  }
}

// ---------------------------------------------------------------------------
// Kernel 3: loss = -mean(num - den) = mean(den - num)
// ---------------------------------------------------------------------------
__global__ __launch_bounds__(64) void loss_kernel(
    const float* __restrict__ num_den, float* __restrict__ out) {
  const int tid = threadIdx.x;
  float v = num_den[64 + tid] - num_den[tid];
#pragma unroll
  for (int off = 32; off >= 1; off >>= 1) v += __shfl_xor(v, off, 64);
  if (tid == 0) out[0] = v * (1.0f / 64.0f);
}

extern "C" void kernel_launch(void* const* d_in, const int* in_sizes, int n_in,
                              void* d_out, int out_size, void* d_ws, size_t ws_size,
                              hipStream_t stream) {
  const float* hidden  = (const float*)d_in[0];
  const int*   mask    = (const int*)d_in[1];
  const int*   labels  = (const int*)d_in[2];
  const float* W       = (const float*)d_in[3];
  const float* bias    = (const float*)d_in[4];
  const float* start_t = (const float*)d_in[5];
  const float* end_t   = (const float*)d_in[6];
  const float* trans   = (const float*)d_in[7];
  float* out = (float*)d_out;

  float* logits  = (float*)d_ws;              // 294912 floats
  float* num_den = logits + (size_t)NROWS * NL; // 128 floats (num[64], den[64])

  logits_kernel<<<1024, 256, 0, stream>>>(hidden, W, bias, logits);
  crf_kernel<<<192, 64, 0, stream>>>(logits, mask, labels, start_t, end_t,
                                     trans, out, num_den);
  loss_kernel<<<1, 64, 0, stream>>>(num_den, out);
}